// Round 4
// baseline (842.725 us; speedup 1.0000x reference)
//
#include <hip/hip_runtime.h>
#include <hip/hip_bf16.h>

#define N_Q     100000
#define N_FEATC 192
#define N_LON   720
#define N_LAT   360
#define HIDD    256
#define OUT_DIM 8
#define M_TILE  64
#define FSTRIDE (N_LON * N_LAT)

typedef float  f32x4  __attribute__((ext_vector_type(4)));
typedef __bf16 bf16x8 __attribute__((ext_vector_type(8)));

__device__ __forceinline__ float gelu_tanh(float x) {
    float u = 0.7978845608028654f * (x + 0.044715f * x * x * x);
    return 0.5f * x * (1.0f + tanhf(u));
}

// numpy f32 constants: pi_f = float32(np.pi); 2*pi_f is exact in f32 and equals
// round(2*pi). deg2rad multiplies by the DOUBLE pi/180 cast to f32 (single op).
#define PI_F      3.14159274101257324219f          /* 0x40490FDB */
#define TWO_PI_F  6.28318548202514648438f          /* 0x40C90FDB */
#define DEG2RAD_F ((float)0.017453292519943295)    /* 0x3C8EFA35 */

// Bit-exact replication of the numpy FLOAT32 argmin (single-mul deg2rad,
// fmodf+adjust remainder, first-occurrence tie-break), over a +-3 window
// around the analytic nearest bin (f32 rounding displaces the argmin by at
// most 1 bin, so the window provably contains it). Contraction OFF so the
// compiler cannot fuse grid*C - q_rad into an FMA (numpy rounds grid*C first).
__device__ __forceinline__ void nearest_lon(
    const float* __restrict__ lon_grid, float lqf, int* idx, float* dlon)
{
#pragma clang fp contract(off)
    float lonq_rad = lqf * DEG2RAD_F;
    int g = (int)floor((double)lqf * 2.0 + 0.5);
    float best = 1e30f; int bi = 0x7fffffff;
    #pragma unroll
    for (int d = -3; d <= 3; ++d) {
        int c = g + d; c %= N_LON; if (c < 0) c += N_LON;
        float lr = lon_grid[c] * DEG2RAD_F;
        float a  = (lr - lonq_rad) + PI_F;
        float m  = fmodf(a, TWO_PI_F);
        if (m < 0.0f) m += TWO_PI_F;               // np.remainder adjust (b > 0)
        float ad = fabsf(m - PI_F);
        if (ad < best || (ad == best && c < bi)) { best = ad; bi = c; }
    }
    *idx = bi;
    *dlon = lqf - lon_grid[bi];                    // UNWRAPPED, as in reference
}

__device__ __forceinline__ void nearest_lat(
    const float* __restrict__ lat_grid, float laf, int* idx, float* dlat)
{
#pragma clang fp contract(off)
    float latq_rad = laf * DEG2RAD_F;
    int gl = (int)floor(((double)laf + 90.0) * (359.0 / 180.0) + 0.5);
    float best = 1e30f; int bi = 0x7fffffff;
    #pragma unroll
    for (int d = -3; d <= 3; ++d) {
        int c = gl + d; c = min(max(c, 0), N_LAT - 1);
        float lr = lat_grid[c] * DEG2RAD_F;
        float ad = fabsf(lr - latq_rad);
        if (ad < best || (ad == best && c < bi)) { best = ad; bi = c; }
    }
    *idx = bi;
    *dlat = laf - lat_grid[bi];
}

// ws layout (bf16 elements): W1t[256][256] | W2t[256][256] | W3t[16][256]
// Wnt[n][k] = Wn[k][n]  (transposed, K-padded with zeros)
__global__ __launch_bounds__(256) void convert_weights(
    const float* __restrict__ W1, const float* __restrict__ W2,
    const float* __restrict__ W3, __bf16* __restrict__ ws)
{
    int idx = blockIdx.x * 256 + threadIdx.x;
    if (idx < 65536) {
        int n = idx >> 8, k = idx & 255;
        float v = (k < 194) ? W1[k * 256 + n] : 0.0f;
        ws[idx] = (__bf16)v;
    } else if (idx < 131072) {
        int j = idx - 65536;
        int n = j >> 8, k = j & 255;
        ws[idx] = (__bf16)W2[k * 256 + n];
    } else if (idx < 135168) {
        int j = idx - 131072;
        int n = j >> 8, k = j & 255;
        float v = (n < 8) ? W3[k * 8 + n] : 0.0f;
        ws[idx] = (__bf16)v;
    }
}

// One K=256 GEMM layer: xin[64][256(pad264)] (bf16, A) x Wt[256][256] (bf16, B^T in ws)
__device__ __forceinline__ void gemm_layer(
    const __bf16* __restrict__ Wt,
    __bf16 (*xin)[264], __bf16 (*wchunk)[40],
    int t, int lane, int r0, f32x4* acc)
{
    for (int kc = 0; kc < 8; ++kc) {
        __syncthreads();
        const int4* src = reinterpret_cast<const int4*>(Wt + t * 256 + kc * 32);
        int4 v0 = src[0], v1 = src[1], v2 = src[2], v3 = src[3];
        int4* dst = reinterpret_cast<int4*>(&wchunk[t][0]);
        dst[0] = v0; dst[1] = v1; dst[2] = v2; dst[3] = v3;
        __syncthreads();
        bf16x8 a = *reinterpret_cast<const bf16x8*>(
            &xin[r0 + (lane & 15)][kc * 32 + (lane >> 4) * 8]);
        #pragma unroll
        for (int nt = 0; nt < 16; ++nt) {
            bf16x8 b = *reinterpret_cast<const bf16x8*>(
                &wchunk[nt * 16 + (lane & 15)][(lane >> 4) * 8]);
            acc[nt] = __builtin_amdgcn_mfma_f32_16x16x32_bf16(a, b, acc[nt], 0, 0, 0);
        }
    }
}

__global__ __launch_bounds__(256) void fused_mlp(
    const float* __restrict__ features, const float* __restrict__ lon_q,
    const float* __restrict__ lat_q, const float* __restrict__ lon_grid,
    const float* __restrict__ lat_grid, const float* __restrict__ W1,
    const float* __restrict__ b1, const float* __restrict__ b2,
    const float* __restrict__ b3, const __bf16* __restrict__ ws,
    float* __restrict__ out)
{
    __shared__ __bf16 xin[M_TILE][264];     // x -> h1 -> h2 (bf16, row pad 264)
    __shared__ __bf16 wchunk[256][40];      // staged B chunk [n=256][k=32] (+8 pad)
    __shared__ float  dlon_s[M_TILE], dlat_s[M_TILE];
    __shared__ int    gbase_s[M_TILE];

    const int t    = threadIdx.x;
    const int lane = t & 63;
    const int wave = t >> 6;
    const int r0   = wave * 16;
    const int m0   = blockIdx.x * M_TILE;

    // ---- index phase ----
    if (t < M_TILE) {
        int q = m0 + t; if (q >= N_Q) q = N_Q - 1;   // tail clamp; stores guarded
        int lon_idx, lat_idx; float dlon, dlat;
        nearest_lon(lon_grid, lon_q[q], &lon_idx, &dlon);
        nearest_lat(lat_grid, lat_q[q], &lat_idx, &dlat);
        gbase_s[t] = lon_idx * N_LAT + lat_idx;
        dlon_s[t] = dlon; dlat_s[t] = dlat;
    }
    __syncthreads();

    // ---- gather: x[q][f] = features[f, lon_idx, lat_idx], bf16 into LDS ----
    {
        int q = t & 63;
        const float* fp = features + gbase_s[q];
        for (int f = (t >> 6); f < N_FEATC; f += 4)
            xin[q][f] = (__bf16)fp[f * FSTRIDE];
        for (int c = 192 + (t >> 6); c < 264; c += 4)
            xin[q][c] = (__bf16)0.0f;     // zero K-pad (deltas handled in fp32 epilogue)
    }

    const f32x4 vzero = {0.0f, 0.0f, 0.0f, 0.0f};
    f32x4 acc[16];
    #pragma unroll
    for (int i = 0; i < 16; ++i) acc[i] = vzero;

    // ---- layer 1 ----
    gemm_layer(ws, xin, wchunk, t, lane, r0, acc);
    __syncthreads();
    {
        const float* W1d0 = W1 + 192 * 256;
        const float* W1d1 = W1 + 193 * 256;
        #pragma unroll
        for (int nt = 0; nt < 16; ++nt) {
            int col = nt * 16 + (lane & 15);
            float w0 = W1d0[col], w1 = W1d1[col], bb = b1[col];
            #pragma unroll
            for (int r = 0; r < 4; ++r) {
                int row = r0 + (lane >> 4) * 4 + r;
                float v = acc[nt][r] + dlon_s[row] * w0 + dlat_s[row] * w1 + bb;
                xin[row][col] = (__bf16)gelu_tanh(v);
            }
            acc[nt] = vzero;
        }
    }

    // ---- layer 2 ----
    gemm_layer(ws + 65536, xin, wchunk, t, lane, r0, acc);
    __syncthreads();
    #pragma unroll
    for (int nt = 0; nt < 16; ++nt) {
        int col = nt * 16 + (lane & 15);
        float bb = b2[col];
        #pragma unroll
        for (int r = 0; r < 4; ++r) {
            int row = r0 + (lane >> 4) * 4 + r;
            float v = acc[nt][r] + bb;
            xin[row][col] = (__bf16)gelu_tanh(v);
        }
    }
    __syncthreads();

    // ---- layer 3: out = h2 @ W3 + b3 (N padded 8->16) ----
    {
        f32x4 acc3 = vzero;
        const __bf16* W3t = ws + 131072;
        #pragma unroll
        for (int kc = 0; kc < 8; ++kc) {
            bf16x8 a = *reinterpret_cast<const bf16x8*>(
                &xin[r0 + (lane & 15)][kc * 32 + (lane >> 4) * 8]);
            bf16x8 b = *reinterpret_cast<const bf16x8*>(
                W3t + (lane & 15) * 256 + kc * 32 + (lane >> 4) * 8);
            acc3 = __builtin_amdgcn_mfma_f32_16x16x32_bf16(a, b, acc3, 0, 0, 0);
        }
        int col = lane & 15;
        if (col < OUT_DIM) {
            float bb = b3[col];
            #pragma unroll
            for (int r = 0; r < 4; ++r) {
                int row = m0 + r0 + (lane >> 4) * 4 + r;
                if (row < N_Q) out[row * OUT_DIM + col] = acc3[r] + bb;
            }
        }
    }
}

// fp32 fixup for wrap-longitude queries (|dlon| > 1): bf16 abs error scales with
// activation magnitude (~26-90 here) and would blow the absmax threshold.
// One wave checks 64 queries; flagged ones (~0.07%) recomputed fully in fp32.
__global__ __launch_bounds__(64) void fixup_fp32(
    const float* __restrict__ features, const float* __restrict__ lon_q,
    const float* __restrict__ lat_q, const float* __restrict__ lon_grid,
    const float* __restrict__ lat_grid,
    const float* __restrict__ W1, const float* __restrict__ b1,
    const float* __restrict__ W2, const float* __restrict__ b2,
    const float* __restrict__ W3, const float* __restrict__ b3,
    float* __restrict__ out)
{
    const int lane = threadIdx.x;
    const int q0   = blockIdx.x * 64;
    int q = q0 + lane; if (q >= N_Q) q = N_Q - 1;

    int lon_idx, lat_idx; float dlon, dlat;
    nearest_lon(lon_grid, lon_q[q], &lon_idx, &dlon);
    bool need = (fabsf(dlon) > 1.0f) && (q0 + lane < N_Q);
    unsigned long long mask = __ballot(need);
    if (mask == 0ULL) return;
    nearest_lat(lat_grid, lat_q[q], &lat_idx, &dlat);
    int gbase = lon_idx * N_LAT + lat_idx;

    __shared__ float xs[194];
    __shared__ float h1s[HIDD];
    __shared__ float h2s[HIDD];

    while (mask) {
        int i = __ffsll((unsigned long long)mask) - 1;
        mask &= mask - 1;
        int   qq    = q0 + i;
        int   gb    = __shfl(gbase, i);
        float fdlon = __shfl(dlon, i);
        float fdlat = __shfl(dlat, i);

        for (int f = lane; f < N_FEATC; f += 64) xs[f] = features[f * FSTRIDE + gb];
        if (lane == 0) { xs[192] = fdlon; xs[193] = fdlat; }
        __syncthreads();

        #pragma unroll
        for (int c = 0; c < 4; ++c) {
            int col = lane + c * 64;
            float acc = b1[col];
            for (int k = 0; k < 194; ++k) acc = fmaf(xs[k], W1[k * 256 + col], acc);
            h1s[col] = gelu_tanh(acc);
        }
        __syncthreads();
        #pragma unroll
        for (int c = 0; c < 4; ++c) {
            int col = lane + c * 64;
            float acc = b2[col];
            for (int k = 0; k < 256; ++k) acc = fmaf(h1s[k], W2[k * 256 + col], acc);
            h2s[col] = gelu_tanh(acc);
        }
        __syncthreads();
        {
            int j = lane & 7, ch = lane >> 3;
            float acc = 0.0f;
            for (int k = ch * 32; k < ch * 32 + 32; ++k)
                acc = fmaf(h2s[k], W3[k * 8 + j], acc);
            #pragma unroll
            for (int off = 8; off < 64; off <<= 1) acc += __shfl_down(acc, off);
            if (lane < 8) out[qq * 8 + lane] = acc + b3[lane];
        }
        __syncthreads();
    }
}

extern "C" void kernel_launch(void* const* d_in, const int* in_sizes, int n_in,
                              void* d_out, int out_size, void* d_ws, size_t ws_size,
                              hipStream_t stream)
{
    const float* features = (const float*)d_in[0];
    const float* lon_q    = (const float*)d_in[1];
    const float* lat_q    = (const float*)d_in[2];
    const float* lon_grid = (const float*)d_in[3];
    const float* lat_grid = (const float*)d_in[4];
    const float* W1       = (const float*)d_in[5];
    const float* b1       = (const float*)d_in[6];
    const float* W2       = (const float*)d_in[7];
    const float* b2       = (const float*)d_in[8];
    const float* W3       = (const float*)d_in[9];
    const float* b3       = (const float*)d_in[10];
    __bf16* ws = (__bf16*)d_ws;
    float* out = (float*)d_out;

    convert_weights<<<528, 256, 0, stream>>>(W1, W2, W3, ws);
    int nblocks = (N_Q + M_TILE - 1) / M_TILE;
    fused_mlp<<<nblocks, 256, 0, stream>>>(features, lon_q, lat_q, lon_grid, lat_grid,
                                           W1, b1, b2, b3, ws, out);
    fixup_fp32<<<nblocks, 64, 0, stream>>>(features, lon_q, lat_q, lon_grid, lat_grid,
                                           W1, b1, W2, b2, W3, b3, out);
}

// Round 6
// 781.128 us; speedup vs baseline: 1.0789x; 1.0789x over previous
//
#include <hip/hip_runtime.h>
#include <hip/hip_bf16.h>

#define N_Q     100000
#define N_FEATC 192
#define N_LON   720
#define N_LAT   360
#define N_CELLS (N_LON * N_LAT)
#define HIDD    256
#define OUT_DIM 8
#define M_TILE  64
#define FSTRIDE N_CELLS

typedef float  f32x4  __attribute__((ext_vector_type(4)));
typedef __bf16 bf16x8 __attribute__((ext_vector_type(8)));

__device__ __forceinline__ float gelu_tanh(float x) {
    float u = 0.7978845608028654f * (x + 0.044715f * x * x * x);
    return 0.5f * x * (1.0f + tanhf(u));
}

// numpy f32 constants: pi_f = float32(np.pi); 2*pi_f is exact in f32.
// deg2rad multiplies by the DOUBLE pi/180 cast to f32 (single op).
#define PI_F      3.14159274101257324219f          /* 0x40490FDB */
#define TWO_PI_F  6.28318548202514648438f          /* 0x40C90FDB */
#define DEG2RAD_F ((float)0.017453292519943295)    /* 0x3C8EFA35 */

// ===== LOCKED (round 4, absmax 0.0156): bit-exact numpy-f32 argmin. =====
// Single-mul deg2rad, fmodf+adjust remainder, first-occurrence tie-break,
// contraction OFF, +-3 window around analytic bin. DO NOT TOUCH.
__device__ __forceinline__ void nearest_lon(
    const float* __restrict__ lon_grid, float lqf, int* idx, float* dlon)
{
#pragma clang fp contract(off)
    float lonq_rad = lqf * DEG2RAD_F;
    int g = (int)floor((double)lqf * 2.0 + 0.5);
    float best = 1e30f; int bi = 0x7fffffff;
    #pragma unroll
    for (int d = -3; d <= 3; ++d) {
        int c = g + d; c %= N_LON; if (c < 0) c += N_LON;
        float lr = lon_grid[c] * DEG2RAD_F;
        float a  = (lr - lonq_rad) + PI_F;
        float m  = fmodf(a, TWO_PI_F);
        if (m < 0.0f) m += TWO_PI_F;               // np.remainder adjust (b > 0)
        float ad = fabsf(m - PI_F);
        if (ad < best || (ad == best && c < bi)) { best = ad; bi = c; }
    }
    *idx = bi;
    *dlon = lqf - lon_grid[bi];                    // UNWRAPPED, as in reference
}

__device__ __forceinline__ void nearest_lat(
    const float* __restrict__ lat_grid, float laf, int* idx, float* dlat)
{
#pragma clang fp contract(off)
    float latq_rad = laf * DEG2RAD_F;
    int gl = (int)floor(((double)laf + 90.0) * (359.0 / 180.0) + 0.5);
    float best = 1e30f; int bi = 0x7fffffff;
    #pragma unroll
    for (int d = -3; d <= 3; ++d) {
        int c = gl + d; c = min(max(c, 0), N_LAT - 1);
        float lr = lat_grid[c] * DEG2RAD_F;
        float ad = fabsf(lr - latq_rad);
        if (ad < best || (ad == best && c < bi)) { best = ad; bi = c; }
    }
    *idx = bi;
    *dlat = laf - lat_grid[bi];
}

// ws layout (bf16 elements): W1t[256][256] | W2t[256][256] | W3t[16][256] | ft[259200][192]
__global__ __launch_bounds__(256) void convert_weights(
    const float* __restrict__ W1, const float* __restrict__ W2,
    const float* __restrict__ W3, __bf16* __restrict__ ws)
{
    int idx = blockIdx.x * 256 + threadIdx.x;
    if (idx < 65536) {
        int n = idx >> 8, k = idx & 255;
        float v = (k < 194) ? W1[k * 256 + n] : 0.0f;
        ws[idx] = (__bf16)v;
    } else if (idx < 131072) {
        int j = idx - 65536;
        int n = j >> 8, k = j & 255;
        ws[idx] = (__bf16)W2[k * 256 + n];
    } else if (idx < 135168) {
        int j = idx - 131072;
        int n = j >> 8, k = j & 255;
        float v = (n < 8) ? W3[k * 8 + n] : 0.0f;
        ws[idx] = (__bf16)v;
    }
}

// features[192][259200] fp32  ->  ft[259200][192] bf16.
// Thread owns 4 consecutive cells; per 8-feature chunk: 8 coalesced float4
// loads, 4 16 B stores into the wave's 24 KB L2-resident output region.
__global__ __launch_bounds__(256) void transpose_features(
    const float* __restrict__ features, __bf16* __restrict__ ft)
{
    int c0 = (blockIdx.x * 256 + threadIdx.x) * 4;
    if (c0 >= N_CELLS) return;
    for (int fc = 0; fc < 24; ++fc) {
        int f0 = fc * 8;
        float4 v[8];
        #pragma unroll
        for (int j = 0; j < 8; ++j)
            v[j] = *reinterpret_cast<const float4*>(
                features + (size_t)(f0 + j) * N_CELLS + c0);
        #pragma unroll
        for (int cc = 0; cc < 4; ++cc) {
            bf16x8 o;
            #pragma unroll
            for (int j = 0; j < 8; ++j)
                o[j] = (__bf16)(reinterpret_cast<const float*>(&v[j]))[cc];
            *reinterpret_cast<bf16x8*>(ft + (size_t)(c0 + cc) * N_FEATC + f0) = o;
        }
    }
}

// One K=256 GEMM layer: xin[64][256(pad264)] (bf16, A) x Wt[256][256] (bf16, B^T in ws)
__device__ __forceinline__ void gemm_layer(
    const __bf16* __restrict__ Wt,
    __bf16 (*xin)[264], __bf16 (*wchunk)[40],
    int t, int lane, int r0, f32x4* acc)
{
    for (int kc = 0; kc < 8; ++kc) {
        __syncthreads();
        const int4* src = reinterpret_cast<const int4*>(Wt + t * 256 + kc * 32);
        int4 v0 = src[0], v1 = src[1], v2 = src[2], v3 = src[3];
        int4* dst = reinterpret_cast<int4*>(&wchunk[t][0]);
        dst[0] = v0; dst[1] = v1; dst[2] = v2; dst[3] = v3;
        __syncthreads();
        bf16x8 a = *reinterpret_cast<const bf16x8*>(
            &xin[r0 + (lane & 15)][kc * 32 + (lane >> 4) * 8]);
        #pragma unroll
        for (int nt = 0; nt < 16; ++nt) {
            bf16x8 b = *reinterpret_cast<const bf16x8*>(
                &wchunk[nt * 16 + (lane & 15)][(lane >> 4) * 8]);
            acc[nt] = __builtin_amdgcn_mfma_f32_16x16x32_bf16(a, b, acc[nt], 0, 0, 0);
        }
    }
}

__global__ __launch_bounds__(256) void fused_mlp(
    const float* __restrict__ features, const float* __restrict__ lon_q,
    const float* __restrict__ lat_q, const float* __restrict__ lon_grid,
    const float* __restrict__ lat_grid, const float* __restrict__ W1,
    const float* __restrict__ b1, const float* __restrict__ b2,
    const float* __restrict__ b3, const __bf16* __restrict__ ws,
    const __bf16* __restrict__ ft, int use_ft,
    float* __restrict__ out)
{
    __shared__ __bf16 xin[M_TILE][264];     // x -> h1 -> h2 (bf16, row pad 264)
    __shared__ __bf16 wchunk[256][40];      // staged B chunk [n=256][k=32] (+8 pad)
    __shared__ float  dlon_s[M_TILE], dlat_s[M_TILE];
    __shared__ int    gbase_s[M_TILE];

    const int t    = threadIdx.x;
    const int lane = t & 63;
    const int wave = t >> 6;
    const int r0   = wave * 16;
    const int m0   = blockIdx.x * M_TILE;

    // ---- index phase ----
    if (t < M_TILE) {
        int q = m0 + t; if (q >= N_Q) q = N_Q - 1;   // tail clamp; stores guarded
        int lon_idx, lat_idx; float dlon, dlat;
        nearest_lon(lon_grid, lon_q[q], &lon_idx, &dlon);
        nearest_lat(lat_grid, lat_q[q], &lat_idx, &dlat);
        gbase_s[t] = lon_idx * N_LAT + lat_idx;
        dlon_s[t] = dlon; dlat_s[t] = dlat;
    }
    __syncthreads();

    // ---- gather x[q][0..191] ----
    if (use_ft) {
        // contiguous 384 B per query; 4 threads/query x 96 B (6 x int4) each
        int q = t >> 2, ch = t & 3;
        const int4* src = reinterpret_cast<const int4*>(
            ft + (size_t)gbase_s[q] * N_FEATC + ch * 48);
        int4* dst = reinterpret_cast<int4*>(&xin[q][ch * 48]);
        #pragma unroll
        for (int j = 0; j < 6; ++j) dst[j] = src[j];
    } else {
        // fallback: strided scalar gather from original layout
        int q = t & 63;
        const float* fp = features + gbase_s[q];
        for (int f = (t >> 6); f < N_FEATC; f += 4)
            xin[q][f] = (__bf16)fp[f * FSTRIDE];
    }
    {   // zero K-pad cols 192..263 (deltas handled in fp32 epilogue)
        int q = t & 63;
        for (int c = 192 + (t >> 6); c < 264; c += 4)
            xin[q][c] = (__bf16)0.0f;
    }

    const f32x4 vzero = {0.0f, 0.0f, 0.0f, 0.0f};
    f32x4 acc[16];
    #pragma unroll
    for (int i = 0; i < 16; ++i) acc[i] = vzero;

    // ---- layer 1 ----
    gemm_layer(ws, xin, wchunk, t, lane, r0, acc);
    __syncthreads();
    {
        const float* W1d0 = W1 + 192 * 256;
        const float* W1d1 = W1 + 193 * 256;
        #pragma unroll
        for (int nt = 0; nt < 16; ++nt) {
            int col = nt * 16 + (lane & 15);
            float w0 = W1d0[col], w1 = W1d1[col], bb = b1[col];
            #pragma unroll
            for (int r = 0; r < 4; ++r) {
                int row = r0 + (lane >> 4) * 4 + r;
                float v = acc[nt][r] + dlon_s[row] * w0 + dlat_s[row] * w1 + bb;
                xin[row][col] = (__bf16)gelu_tanh(v);
            }
            acc[nt] = vzero;
        }
    }

    // ---- layer 2 ----
    gemm_layer(ws + 65536, xin, wchunk, t, lane, r0, acc);
    __syncthreads();
    #pragma unroll
    for (int nt = 0; nt < 16; ++nt) {
        int col = nt * 16 + (lane & 15);
        float bb = b2[col];
        #pragma unroll
        for (int r = 0; r < 4; ++r) {
            int row = r0 + (lane >> 4) * 4 + r;
            float v = acc[nt][r] + bb;
            xin[row][col] = (__bf16)gelu_tanh(v);
        }
    }
    __syncthreads();

    // ---- layer 3: out = h2 @ W3 + b3 (N padded 8->16) ----
    {
        f32x4 acc3 = vzero;
        const __bf16* W3t = ws + 131072;
        #pragma unroll
        for (int kc = 0; kc < 8; ++kc) {
            bf16x8 a = *reinterpret_cast<const bf16x8*>(
                &xin[r0 + (lane & 15)][kc * 32 + (lane >> 4) * 8]);
            bf16x8 b = *reinterpret_cast<const bf16x8*>(
                W3t + (lane & 15) * 256 + kc * 32 + (lane >> 4) * 8);
            acc3 = __builtin_amdgcn_mfma_f32_16x16x32_bf16(a, b, acc3, 0, 0, 0);
        }
        int col = lane & 15;
        if (col < OUT_DIM) {
            float bb = b3[col];
            #pragma unroll
            for (int r = 0; r < 4; ++r) {
                int row = m0 + r0 + (lane >> 4) * 4 + r;
                if (row < N_Q) out[row * OUT_DIM + col] = acc3[r] + bb;
            }
        }
    }
}

// fp32 fixup for wrap-longitude queries (|dlon| > 1): bf16 abs error scales with
// activation magnitude (~26-90 here). Reads ORIGINAL fp32 features (exact).
__global__ __launch_bounds__(64) void fixup_fp32(
    const float* __restrict__ features, const float* __restrict__ lon_q,
    const float* __restrict__ lat_q, const float* __restrict__ lon_grid,
    const float* __restrict__ lat_grid,
    const float* __restrict__ W1, const float* __restrict__ b1,
    const float* __restrict__ W2, const float* __restrict__ b2,
    const float* __restrict__ W3, const float* __restrict__ b3,
    float* __restrict__ out)
{
    const int lane = threadIdx.x;
    const int q0   = blockIdx.x * 64;
    int q = q0 + lane; if (q >= N_Q) q = N_Q - 1;

    int lon_idx, lat_idx; float dlon, dlat;
    nearest_lon(lon_grid, lon_q[q], &lon_idx, &dlon);
    bool need = (fabsf(dlon) > 1.0f) && (q0 + lane < N_Q);
    unsigned long long mask = __ballot(need);
    if (mask == 0ULL) return;
    nearest_lat(lat_grid, lat_q[q], &lat_idx, &dlat);
    int gbase = lon_idx * N_LAT + lat_idx;

    __shared__ float xs[194];
    __shared__ float h1s[HIDD];
    __shared__ float h2s[HIDD];

    while (mask) {
        int i = __ffsll((unsigned long long)mask) - 1;
        mask &= mask - 1;
        int   qq    = q0 + i;
        int   gb    = __shfl(gbase, i);
        float fdlon = __shfl(dlon, i);
        float fdlat = __shfl(dlat, i);

        for (int f = lane; f < N_FEATC; f += 64) xs[f] = features[f * FSTRIDE + gb];
        if (lane == 0) { xs[192] = fdlon; xs[193] = fdlat; }
        __syncthreads();

        #pragma unroll
        for (int c = 0; c < 4; ++c) {
            int col = lane + c * 64;
            float acc = b1[col];
            for (int k = 0; k < 194; ++k) acc = fmaf(xs[k], W1[k * 256 + col], acc);
            h1s[col] = gelu_tanh(acc);
        }
        __syncthreads();
        #pragma unroll
        for (int c = 0; c < 4; ++c) {
            int col = lane + c * 64;
            float acc = b2[col];
            for (int k = 0; k < 256; ++k) acc = fmaf(h1s[k], W2[k * 256 + col], acc);
            h2s[col] = gelu_tanh(acc);
        }
        __syncthreads();
        {
            int j = lane & 7, ch = lane >> 3;
            float acc = 0.0f;
            for (int k = ch * 32; k < ch * 32 + 32; ++k)
                acc = fmaf(h2s[k], W3[k * 8 + j], acc);
            #pragma unroll
            for (int off = 8; off < 64; off <<= 1) acc += __shfl_down(acc, off);
            if (lane < 8) out[qq * 8 + lane] = acc + b3[lane];
        }
        __syncthreads();
    }
}

extern "C" void kernel_launch(void* const* d_in, const int* in_sizes, int n_in,
                              void* d_out, int out_size, void* d_ws, size_t ws_size,
                              hipStream_t stream)
{
    const float* features = (const float*)d_in[0];
    const float* lon_q    = (const float*)d_in[1];
    const float* lat_q    = (const float*)d_in[2];
    const float* lon_grid = (const float*)d_in[3];
    const float* lat_grid = (const float*)d_in[4];
    const float* W1       = (const float*)d_in[5];
    const float* b1       = (const float*)d_in[6];
    const float* W2       = (const float*)d_in[7];
    const float* b2       = (const float*)d_in[8];
    const float* W3       = (const float*)d_in[9];
    const float* b3       = (const float*)d_in[10];
    __bf16* ws = (__bf16*)d_ws;
    float* out = (float*)d_out;

    const size_t need = 135168ull * 2 + (size_t)N_CELLS * N_FEATC * 2;  // ~95.2 MiB
    const int use_ft = (ws_size >= need) ? 1 : 0;
    __bf16* ft = ws + 135168;

    convert_weights<<<528, 256, 0, stream>>>(W1, W2, W3, ws);
    if (use_ft) {
        int tb = (N_CELLS / 4 + 255) / 256;
        transpose_features<<<tb, 256, 0, stream>>>(features, ft);
    }
    int nblocks = (N_Q + M_TILE - 1) / M_TILE;
    fused_mlp<<<nblocks, 256, 0, stream>>>(features, lon_q, lat_q, lon_grid, lat_grid,
                                           W1, b1, b2, b3, ws, ft, use_ft, out);
    fixup_fp32<<<nblocks, 64, 0, stream>>>(features, lon_q, lat_q, lon_grid, lat_grid,
                                           W1, b1, W2, b2, W3, b3, out);
}

// Round 7
// 606.153 us; speedup vs baseline: 1.3903x; 1.2887x over previous
//
#include <hip/hip_runtime.h>
#include <hip/hip_bf16.h>

#define N_Q     100000
#define N_FEATC 192
#define N_LON   720
#define N_LAT   360
#define N_CELLS (N_LON * N_LAT)
#define HIDD    256
#define OUT_DIM 8
#define M_TILE  64
#define FSTRIDE N_CELLS

typedef float  f32x4  __attribute__((ext_vector_type(4)));
typedef __bf16 bf16x8 __attribute__((ext_vector_type(8)));

__device__ __forceinline__ float gelu_tanh(float x) {
    float u = 0.7978845608028654f * (x + 0.044715f * x * x * x);
    return 0.5f * x * (1.0f + tanhf(u));
}

// numpy f32 constants: pi_f = float32(np.pi); 2*pi_f is exact in f32.
// deg2rad multiplies by the DOUBLE pi/180 cast to f32 (single op).
#define PI_F      3.14159274101257324219f          /* 0x40490FDB */
#define TWO_PI_F  6.28318548202514648438f          /* 0x40C90FDB */
#define DEG2RAD_F ((float)0.017453292519943295)    /* 0x3C8EFA35 */

// ===== LOCKED (round 4, absmax 0.0156): bit-exact numpy-f32 argmin. =====
// Single-mul deg2rad, fmodf+adjust remainder, first-occurrence tie-break,
// contraction OFF, +-3 window around analytic bin. DO NOT TOUCH.
__device__ __forceinline__ void nearest_lon(
    const float* __restrict__ lon_grid, float lqf, int* idx, float* dlon)
{
#pragma clang fp contract(off)
    float lonq_rad = lqf * DEG2RAD_F;
    int g = (int)floor((double)lqf * 2.0 + 0.5);
    float best = 1e30f; int bi = 0x7fffffff;
    #pragma unroll
    for (int d = -3; d <= 3; ++d) {
        int c = g + d; c %= N_LON; if (c < 0) c += N_LON;
        float lr = lon_grid[c] * DEG2RAD_F;
        float a  = (lr - lonq_rad) + PI_F;
        float m  = fmodf(a, TWO_PI_F);
        if (m < 0.0f) m += TWO_PI_F;               // np.remainder adjust (b > 0)
        float ad = fabsf(m - PI_F);
        if (ad < best || (ad == best && c < bi)) { best = ad; bi = c; }
    }
    *idx = bi;
    *dlon = lqf - lon_grid[bi];                    // UNWRAPPED, as in reference
}

__device__ __forceinline__ void nearest_lat(
    const float* __restrict__ lat_grid, float laf, int* idx, float* dlat)
{
#pragma clang fp contract(off)
    float latq_rad = laf * DEG2RAD_F;
    int gl = (int)floor(((double)laf + 90.0) * (359.0 / 180.0) + 0.5);
    float best = 1e30f; int bi = 0x7fffffff;
    #pragma unroll
    for (int d = -3; d <= 3; ++d) {
        int c = gl + d; c = min(max(c, 0), N_LAT - 1);
        float lr = lat_grid[c] * DEG2RAD_F;
        float ad = fabsf(lr - latq_rad);
        if (ad < best || (ad == best && c < bi)) { best = ad; bi = c; }
    }
    *idx = bi;
    *dlat = laf - lat_grid[bi];
}

// ws layout (bf16 elements): W1t[256][256] | W2t[256][256] | W3t[16][256] | ft[259200][192]
__global__ __launch_bounds__(256) void convert_weights(
    const float* __restrict__ W1, const float* __restrict__ W2,
    const float* __restrict__ W3, __bf16* __restrict__ ws)
{
    int idx = blockIdx.x * 256 + threadIdx.x;
    if (idx < 65536) {
        int n = idx >> 8, k = idx & 255;
        float v = (k < 194) ? W1[k * 256 + n] : 0.0f;
        ws[idx] = (__bf16)v;
    } else if (idx < 131072) {
        int j = idx - 65536;
        int n = j >> 8, k = j & 255;
        ws[idx] = (__bf16)W2[k * 256 + n];
    } else if (idx < 135168) {
        int j = idx - 131072;
        int n = j >> 8, k = j & 255;
        float v = (n < 8) ? W3[k * 8 + n] : 0.0f;
        ws[idx] = (__bf16)v;
    }
}

// features[192][259200] fp32  ->  ft[259200][192] bf16.
__global__ __launch_bounds__(256) void transpose_features(
    const float* __restrict__ features, __bf16* __restrict__ ft)
{
    int c0 = (blockIdx.x * 256 + threadIdx.x) * 4;
    if (c0 >= N_CELLS) return;
    for (int fc = 0; fc < 24; ++fc) {
        int f0 = fc * 8;
        float4 v[8];
        #pragma unroll
        for (int j = 0; j < 8; ++j)
            v[j] = *reinterpret_cast<const float4*>(
                features + (size_t)(f0 + j) * N_CELLS + c0);
        #pragma unroll
        for (int cc = 0; cc < 4; ++cc) {
            bf16x8 o;
            #pragma unroll
            for (int j = 0; j < 8; ++j)
                o[j] = (__bf16)(reinterpret_cast<const float*>(&v[j]))[cc];
            *reinterpret_cast<bf16x8*>(ft + (size_t)(c0 + cc) * N_FEATC + f0) = o;
        }
    }
}

// One K=256 GEMM layer: xin[64][256(pad264)] (bf16, A) x Wt[256][256] (bf16, B^T in ws)
__device__ __forceinline__ void gemm_layer(
    const __bf16* __restrict__ Wt,
    __bf16 (*xin)[264], __bf16 (*wchunk)[40],
    int t, int lane, int r0, f32x4* acc)
{
    for (int kc = 0; kc < 8; ++kc) {
        __syncthreads();
        const int4* src = reinterpret_cast<const int4*>(Wt + t * 256 + kc * 32);
        int4 v0 = src[0], v1 = src[1], v2 = src[2], v3 = src[3];
        int4* dst = reinterpret_cast<int4*>(&wchunk[t][0]);
        dst[0] = v0; dst[1] = v1; dst[2] = v2; dst[3] = v3;
        __syncthreads();
        bf16x8 a = *reinterpret_cast<const bf16x8*>(
            &xin[r0 + (lane & 15)][kc * 32 + (lane >> 4) * 8]);
        #pragma unroll
        for (int nt = 0; nt < 16; ++nt) {
            bf16x8 b = *reinterpret_cast<const bf16x8*>(
                &wchunk[nt * 16 + (lane & 15)][(lane >> 4) * 8]);
            acc[nt] = __builtin_amdgcn_mfma_f32_16x16x32_bf16(a, b, acc[nt], 0, 0, 0);
        }
    }
}

__global__ __launch_bounds__(256) void fused_mlp(
    const float* __restrict__ features, const float* __restrict__ lon_q,
    const float* __restrict__ lat_q, const float* __restrict__ lon_grid,
    const float* __restrict__ lat_grid, const float* __restrict__ W1,
    const float* __restrict__ b1, const float* __restrict__ b2,
    const float* __restrict__ b3, const __bf16* __restrict__ ws,
    const __bf16* __restrict__ ft, int use_ft,
    float* __restrict__ out)
{
    __shared__ __bf16 xin[M_TILE][264];     // x -> h1 -> h2 (bf16, row pad 264)
    __shared__ __bf16 wchunk[256][40];      // staged B chunk [n=256][k=32] (+8 pad)
    __shared__ float  dlon_s[M_TILE], dlat_s[M_TILE];
    __shared__ int    gbase_s[M_TILE];

    const int t    = threadIdx.x;
    const int lane = t & 63;
    const int wave = t >> 6;
    const int r0   = wave * 16;
    const int m0   = blockIdx.x * M_TILE;

    // ---- index phase ----
    if (t < M_TILE) {
        int q = m0 + t; if (q >= N_Q) q = N_Q - 1;   // tail clamp; stores guarded
        int lon_idx, lat_idx; float dlon, dlat;
        nearest_lon(lon_grid, lon_q[q], &lon_idx, &dlon);
        nearest_lat(lat_grid, lat_q[q], &lat_idx, &dlat);
        gbase_s[t] = lon_idx * N_LAT + lat_idx;
        dlon_s[t] = dlon; dlat_s[t] = dlat;
    }
    __syncthreads();

    // ---- gather x[q][0..191] ----
    if (use_ft) {
        // contiguous 384 B per query; 4 threads/query x 96 B (6 x int4) each
        int q = t >> 2, ch = t & 3;
        const int4* src = reinterpret_cast<const int4*>(
            ft + (size_t)gbase_s[q] * N_FEATC + ch * 48);
        int4* dst = reinterpret_cast<int4*>(&xin[q][ch * 48]);
        #pragma unroll
        for (int j = 0; j < 6; ++j) dst[j] = src[j];
    } else {
        // fallback: strided scalar gather from original layout
        int q = t & 63;
        const float* fp = features + gbase_s[q];
        for (int f = (t >> 6); f < N_FEATC; f += 4)
            xin[q][f] = (__bf16)fp[f * FSTRIDE];
    }
    {   // zero K-pad cols 192..263 (deltas handled in fp32 epilogue)
        int q = t & 63;
        for (int c = 192 + (t >> 6); c < 264; c += 4)
            xin[q][c] = (__bf16)0.0f;
    }

    const f32x4 vzero = {0.0f, 0.0f, 0.0f, 0.0f};
    f32x4 acc[16];
    #pragma unroll
    for (int i = 0; i < 16; ++i) acc[i] = vzero;

    // ---- layer 1 ----
    gemm_layer(ws, xin, wchunk, t, lane, r0, acc);
    __syncthreads();
    {
        const float* W1d0 = W1 + 192 * 256;
        const float* W1d1 = W1 + 193 * 256;
        #pragma unroll
        for (int nt = 0; nt < 16; ++nt) {
            int col = nt * 16 + (lane & 15);
            float w0 = W1d0[col], w1 = W1d1[col], bb = b1[col];
            #pragma unroll
            for (int r = 0; r < 4; ++r) {
                int row = r0 + (lane >> 4) * 4 + r;
                float v = acc[nt][r] + dlon_s[row] * w0 + dlat_s[row] * w1 + bb;
                xin[row][col] = (__bf16)gelu_tanh(v);
            }
            acc[nt] = vzero;
        }
    }

    // ---- layer 2 ----
    gemm_layer(ws + 65536, xin, wchunk, t, lane, r0, acc);
    __syncthreads();
    #pragma unroll
    for (int nt = 0; nt < 16; ++nt) {
        int col = nt * 16 + (lane & 15);
        float bb = b2[col];
        #pragma unroll
        for (int r = 0; r < 4; ++r) {
            int row = r0 + (lane >> 4) * 4 + r;
            float v = acc[nt][r] + bb;
            xin[row][col] = (__bf16)gelu_tanh(v);
        }
    }
    __syncthreads();

    // ---- layer 3: out = h2 @ W3 + b3 (N padded 8->16) ----
    {
        f32x4 acc3 = vzero;
        const __bf16* W3t = ws + 131072;
        #pragma unroll
        for (int kc = 0; kc < 8; ++kc) {
            bf16x8 a = *reinterpret_cast<const bf16x8*>(
                &xin[r0 + (lane & 15)][kc * 32 + (lane >> 4) * 8]);
            bf16x8 b = *reinterpret_cast<const bf16x8*>(
                W3t + (lane & 15) * 256 + kc * 32 + (lane >> 4) * 8);
            acc3 = __builtin_amdgcn_mfma_f32_16x16x32_bf16(a, b, acc3, 0, 0, 0);
        }
        int col = lane & 15;
        if (col < OUT_DIM) {
            float bb = b3[col];
            #pragma unroll
            for (int r = 0; r < 4; ++r) {
                int row = m0 + r0 + (lane >> 4) * 4 + r;
                if (row < N_Q) out[row * OUT_DIM + col] = acc3[r] + bb;
            }
        }
    }
}

// fp32 fixup for wrap-longitude queries (|dlon| > 1). Round-6 counters showed
// the old 64-thread version was latency-serialized (225 us, VALUBusy 0.4%,
// occ 0.8%): ~450 dependent W-load groups x ~900 cyc. Rewrite: 256 threads
// (1 col/thread/layer, 4 waves TLP) + 16-way batched W loads (ILP 16).
__global__ __launch_bounds__(256) void fixup_fp32(
    const float* __restrict__ features, const float* __restrict__ lon_q,
    const float* __restrict__ lat_q, const float* __restrict__ lon_grid,
    const float* __restrict__ lat_grid,
    const float* __restrict__ W1, const float* __restrict__ b1,
    const float* __restrict__ W2, const float* __restrict__ b2,
    const float* __restrict__ W3, const float* __restrict__ b3,
    float* __restrict__ out)
{
    const int t  = threadIdx.x;
    const int q0 = blockIdx.x * 64;

    __shared__ int   nflag;
    __shared__ int   fgb[64];
    __shared__ float fdl[64], fdt[64];
    __shared__ int   fqi[64];

    if (t == 0) nflag = 0;
    __syncthreads();
    if (t < 64) {
        int q = q0 + t;
        if (q < N_Q) {
            int lon_idx; float dlon;
            nearest_lon(lon_grid, lon_q[q], &lon_idx, &dlon);
            if (fabsf(dlon) > 1.0f) {
                int lat_idx; float dlat;
                nearest_lat(lat_grid, lat_q[q], &lat_idx, &dlat);
                int slot = atomicAdd(&nflag, 1);
                fqi[slot] = q;
                fgb[slot] = lon_idx * N_LAT + lat_idx;
                fdl[slot] = dlon; fdt[slot] = dlat;
            }
        }
    }
    __syncthreads();
    const int n = nflag;
    if (n == 0) return;

    __shared__ float xs[194];
    __shared__ float h1s[HIDD];
    __shared__ float h2s[HIDD];

    for (int i = 0; i < n; ++i) {
        int gb = fgb[i];
        if (t < 194)
            xs[t] = (t < 192) ? features[(size_t)t * FSTRIDE + gb]
                              : (t == 192 ? fdl[i] : fdt[i]);
        __syncthreads();

        // layer 1: col = t, k-loop batched by 16 (loads hoisted ahead of FMAs)
        {
            float acc = b1[t];
            int k = 0;
            for (; k + 16 <= 194; k += 16) {
                float w[16];
                #pragma unroll
                for (int u = 0; u < 16; ++u) w[u] = W1[(k + u) * 256 + t];
                #pragma unroll
                for (int u = 0; u < 16; ++u) acc = fmaf(xs[k + u], w[u], acc);
            }
            for (; k < 194; ++k) acc = fmaf(xs[k], W1[k * 256 + t], acc);
            h1s[t] = gelu_tanh(acc);
        }
        __syncthreads();

        // layer 2
        {
            float acc = b2[t];
            for (int k = 0; k < 256; k += 16) {
                float w[16];
                #pragma unroll
                for (int u = 0; u < 16; ++u) w[u] = W2[(k + u) * 256 + t];
                #pragma unroll
                for (int u = 0; u < 16; ++u) acc = fmaf(h1s[k + u], w[u], acc);
            }
            h2s[t] = gelu_tanh(acc);
        }
        __syncthreads();

        // layer 3: wave 0, 8 lanes/output x 8 outputs, 32 elems each, shfl-reduce
        if (t < 64) {
            int j = t & 7, ch = t >> 3;
            float a3 = 0.0f;
            for (int k = ch * 32; k < ch * 32 + 32; ++k)
                a3 = fmaf(h2s[k], W3[k * 8 + j], a3);
            #pragma unroll
            for (int off = 8; off < 64; off <<= 1) a3 += __shfl_down(a3, off);
            if (t < 8) out[fqi[i] * 8 + t] = a3 + b3[t];
        }
        __syncthreads();
    }
}

extern "C" void kernel_launch(void* const* d_in, const int* in_sizes, int n_in,
                              void* d_out, int out_size, void* d_ws, size_t ws_size,
                              hipStream_t stream)
{
    const float* features = (const float*)d_in[0];
    const float* lon_q    = (const float*)d_in[1];
    const float* lat_q    = (const float*)d_in[2];
    const float* lon_grid = (const float*)d_in[3];
    const float* lat_grid = (const float*)d_in[4];
    const float* W1       = (const float*)d_in[5];
    const float* b1       = (const float*)d_in[6];
    const float* W2       = (const float*)d_in[7];
    const float* b2       = (const float*)d_in[8];
    const float* W3       = (const float*)d_in[9];
    const float* b3       = (const float*)d_in[10];
    __bf16* ws = (__bf16*)d_ws;
    float* out = (float*)d_out;

    const size_t need = 135168ull * 2 + (size_t)N_CELLS * N_FEATC * 2;  // ~95.2 MiB
    const int use_ft = (ws_size >= need) ? 1 : 0;
    __bf16* ft = ws + 135168;

    convert_weights<<<528, 256, 0, stream>>>(W1, W2, W3, ws);
    if (use_ft) {
        int tb = (N_CELLS / 4 + 255) / 256;
        transpose_features<<<tb, 256, 0, stream>>>(features, ft);
    }
    int nblocks = (N_Q + M_TILE - 1) / M_TILE;
    fused_mlp<<<nblocks, 256, 0, stream>>>(features, lon_q, lat_q, lon_grid, lat_grid,
                                           W1, b1, b2, b3, ws, ft, use_ft, out);
    fixup_fp32<<<nblocks, 256, 0, stream>>>(features, lon_q, lat_q, lon_grid, lat_grid,
                                            W1, b1, W2, b2, W3, b3, out);
}